// Round 1
// baseline (2400.920 us; speedup 1.0000x reference)
//
#include <hip/hip_runtime.h>
#include <math.h>

#define NN 100000
#define EE 800000
#define NHEADS 4
#define HID 48
#define FDIM (NHEADS * HID)   // 192
#define ETOT (EE + NN)        // edges + self-loops

// ---- monotone float <-> uint key for atomicMax-based segment max ----
__device__ __forceinline__ unsigned fkey(float f) {
    unsigned b = __float_as_uint(f);
    return (b & 0x80000000u) ? ~b : (b | 0x80000000u);
}
__device__ __forceinline__ float fkeyinv(unsigned k) {
    unsigned b = (k & 0x80000000u) ? (k ^ 0x80000000u) : ~k;
    return __uint_as_float(b);
}

// xl = x@Wl + bl ; xr = x@Wr + br   (W: [DIN, 192] row-major)
template <int DIN>
__global__ void gemm_lr_k(const float* __restrict__ x,
                          const float* __restrict__ Wl, const float* __restrict__ bl,
                          const float* __restrict__ Wr, const float* __restrict__ br,
                          float* __restrict__ xl, float* __restrict__ xr) {
    int t = blockIdx.x * blockDim.x + threadIdx.x;
    if (t >= NN * FDIM) return;
    int n = t / FDIM;
    int j = t - n * FDIM;
    const float* xp = x + (size_t)n * DIN;
    float al = bl[j], ar = br[j];
#pragma unroll
    for (int k = 0; k < DIN; k++) {
        float xv = xp[k];
        al = fmaf(xv, Wl[k * FDIM + j], al);
        ar = fmaf(xv, Wr[k * FDIM + j], ar);
    }
    xl[t] = al;
    xr[t] = ar;
}

// per (edge, head): logit = sum_c leakyrelu(xl[s]+xr[d]) * att[h]; seg-max via atomicMax
__global__ void edge_logits_k(const float* __restrict__ xl, const float* __restrict__ xr,
                              const int* __restrict__ ei, const float* __restrict__ att,
                              float* __restrict__ logits, unsigned* __restrict__ mkey) {
    int t = blockIdx.x * blockDim.x + threadIdx.x;
    if (t >= ETOT * NHEADS) return;
    int e = t >> 2, h = t & 3;
    int s, d;
    if (e < EE) { s = ei[e]; d = ei[EE + e]; }
    else        { s = d = e - EE; }
    const float4* pl = (const float4*)(xl + (size_t)s * FDIM + h * HID);
    const float4* pr = (const float4*)(xr + (size_t)d * FDIM + h * HID);
    const float4* pa = (const float4*)(att + h * HID);
    float acc = 0.f;
#pragma unroll
    for (int q = 0; q < HID / 4; q++) {
        float4 a = pl[q], b = pr[q], w = pa[q];
        float v;
        v = a.x + b.x; v = v > 0.f ? v : 0.2f * v; acc = fmaf(v, w.x, acc);
        v = a.y + b.y; v = v > 0.f ? v : 0.2f * v; acc = fmaf(v, w.y, acc);
        v = a.z + b.z; v = v > 0.f ? v : 0.2f * v; acc = fmaf(v, w.z, acc);
        v = a.w + b.w; v = v > 0.f ? v : 0.2f * v; acc = fmaf(v, w.w, acc);
    }
    logits[t] = acc;
    atomicMax(&mkey[d * NHEADS + h], fkey(acc));
}

// ex = exp(logit - m[dst]); denom[dst] += ex (logits buffer overwritten with ex)
__global__ void edge_expsum_k(const int* __restrict__ ei, const unsigned* __restrict__ mkey,
                              float* __restrict__ logits, float* __restrict__ denom) {
    int t = blockIdx.x * blockDim.x + threadIdx.x;
    if (t >= ETOT * NHEADS) return;
    int e = t >> 2, h = t & 3;
    int d = (e < EE) ? ei[EE + e] : e - EE;
    float m = fkeyinv(mkey[d * NHEADS + h]);
    float ex = expf(logits[t] - m);
    logits[t] = ex;
    atomicAdd(&denom[d * NHEADS + h], ex);
}

// wave per edge: xn[d][c] += 0.25 * sum_h alpha_h * xl[s][h][c]
__global__ void edge_accum_k(const float* __restrict__ xl, const float* __restrict__ ex,
                             const float* __restrict__ denom, const int* __restrict__ ei,
                             float* __restrict__ xn) {
    int gt = blockIdx.x * blockDim.x + threadIdx.x;
    int e = gt >> 6;
    int lane = gt & 63;
    if (e >= ETOT) return;
    int s, d;
    if (e < EE) { s = ei[e]; d = ei[EE + e]; }
    else        { s = d = e - EE; }
    float a0 = ex[e * 4 + 0] / (denom[d * 4 + 0] + 1e-16f);
    float a1 = ex[e * 4 + 1] / (denom[d * 4 + 1] + 1e-16f);
    float a2 = ex[e * 4 + 2] / (denom[d * 4 + 2] + 1e-16f);
    float a3 = ex[e * 4 + 3] / (denom[d * 4 + 3] + 1e-16f);
    if (lane < HID) {
        const float* p = xl + (size_t)s * FDIM;
        float v = a0 * p[lane] + a1 * p[HID + lane] + a2 * p[2 * HID + lane] + a3 * p[3 * HID + lane];
        atomicAdd(&xn[(size_t)d * HID + lane], 0.25f * v);
    }
}

__global__ void bias_elu_k(float* __restrict__ x, const float* __restrict__ b) {
    int t = blockIdx.x * blockDim.x + threadIdx.x;
    if (t >= NN * HID) return;
    int c = t % HID;
    float v = x[t] + b[c];
    x[t] = v > 0.f ? v : expm1f(v);
}

__global__ void head_k(const float* __restrict__ x, const float* __restrict__ w,
                       const float* __restrict__ hb, float* __restrict__ out) {
    int n = blockIdx.x * blockDim.x + threadIdx.x;
    if (n >= NN) return;
    const float* p = x + (size_t)n * HID;
    float acc = 0.f;
#pragma unroll
    for (int c = 0; c < HID; c++) acc = fmaf(p[c], w[c], acc);
    acc += hb[0];
    out[n] = fmaxf(acc, 0.f) + log1pf(expf(-fabsf(acc)));
}

static inline int cdiv(long a, long b) { return (int)((a + b - 1) / b); }

extern "C" void kernel_launch(void* const* d_in, const int* in_sizes, int n_in,
                              void* d_out, int out_size, void* d_ws, size_t ws_size,
                              hipStream_t stream) {
    const float* x0 = (const float*)d_in[0];
    const int* ei = (const int*)d_in[1];
    const float* Wl[3] = {(const float*)d_in[2], (const float*)d_in[8], (const float*)d_in[14]};
    const float* bl[3] = {(const float*)d_in[3], (const float*)d_in[9], (const float*)d_in[15]};
    const float* Wr[3] = {(const float*)d_in[4], (const float*)d_in[10], (const float*)d_in[16]};
    const float* br[3] = {(const float*)d_in[5], (const float*)d_in[11], (const float*)d_in[17]};
    const float* att[3] = {(const float*)d_in[6], (const float*)d_in[12], (const float*)d_in[18]};
    const float* bb[3] = {(const float*)d_in[7], (const float*)d_in[13], (const float*)d_in[19]};
    const float* hw = (const float*)d_in[20];
    const float* hb = (const float*)d_in[21];

    char* ws = (char*)d_ws;
    float* xl = (float*)ws;          ws += (size_t)NN * FDIM * 4;
    float* xr = (float*)ws;          ws += (size_t)NN * FDIM * 4;
    float* logits = (float*)ws;      ws += (size_t)ETOT * NHEADS * 4;
    unsigned* mkey = (unsigned*)ws;  ws += (size_t)NN * NHEADS * 4;
    float* denom = (float*)ws;       ws += (size_t)NN * NHEADS * 4;
    float* bufA = (float*)ws;        ws += (size_t)NN * HID * 4;
    float* bufB = (float*)ws;        ws += (size_t)NN * HID * 4;

    const float* xin = x0;
    float* bufs[2] = {bufA, bufB};

    for (int l = 0; l < 3; l++) {
        float* xout = bufs[l & 1];
        hipMemsetAsync(mkey, 0, (size_t)NN * NHEADS * sizeof(unsigned), stream);
        hipMemsetAsync(denom, 0, (size_t)NN * NHEADS * sizeof(float), stream);
        hipMemsetAsync(xout, 0, (size_t)NN * HID * sizeof(float), stream);
        if (l == 0)
            gemm_lr_k<3><<<cdiv((long)NN * FDIM, 256), 256, 0, stream>>>(
                xin, Wl[0], bl[0], Wr[0], br[0], xl, xr);
        else
            gemm_lr_k<48><<<cdiv((long)NN * FDIM, 256), 256, 0, stream>>>(
                xin, Wl[l], bl[l], Wr[l], br[l], xl, xr);
        edge_logits_k<<<cdiv((long)ETOT * NHEADS, 256), 256, 0, stream>>>(
            xl, xr, ei, att[l], logits, mkey);
        edge_expsum_k<<<cdiv((long)ETOT * NHEADS, 256), 256, 0, stream>>>(
            ei, mkey, logits, denom);
        edge_accum_k<<<cdiv((long)ETOT * 64, 256), 256, 0, stream>>>(
            xl, logits, denom, ei, xout);
        bias_elu_k<<<cdiv((long)NN * HID, 256), 256, 0, stream>>>(xout, bb[l]);
        xin = xout;
    }
    head_k<<<cdiv(NN, 256), 256, 0, stream>>>(xin, hw, hb, (float*)d_out);
}

// Round 2
// 1121.884 us; speedup vs baseline: 2.1401x; 2.1401x over previous
//
#include <hip/hip_runtime.h>
#include <math.h>

#define NN 100000
#define EE 800000
#define NHEADS 4
#define HID 48
#define FDIM (NHEADS * HID)   // 192
#define SCAN_CHUNK 2048
#define NBLK ((NN + SCAN_CHUNK - 1) / SCAN_CHUNK)  // 49

// ---------------- CSR build (by destination), reused across the 3 layers ----------------

__global__ void hist_k(const int* __restrict__ ei, int* __restrict__ cnt) {
    int e = blockIdx.x * blockDim.x + threadIdx.x;
    if (e >= EE) return;
    atomicAdd(&cnt[ei[EE + e]], 1);
}

__global__ void scan1_k(const int* __restrict__ cnt, int* __restrict__ rowptr,
                        int* __restrict__ bsum) {
    __shared__ int lds[256];
    int b = blockIdx.x, t = threadIdx.x;
    int base = b * SCAN_CHUNK + t * 8;
    int v[8], s = 0;
#pragma unroll
    for (int i = 0; i < 8; i++) { v[i] = (base + i < NN) ? cnt[base + i] : 0; s += v[i]; }
    lds[t] = s;
    __syncthreads();
    for (int off = 1; off < 256; off <<= 1) {
        int val = (t >= off) ? lds[t - off] : 0;
        __syncthreads();
        lds[t] += val;
        __syncthreads();
    }
    if (t == 255) bsum[b] = lds[255];
    int run = lds[t] - s;  // exclusive prefix within block
#pragma unroll
    for (int i = 0; i < 8; i++) {
        if (base + i < NN) rowptr[base + i] = run;
        run += v[i];
    }
}

__global__ void scan2_k(int* __restrict__ bsum) {
    if (threadIdx.x == 0 && blockIdx.x == 0) {
        int acc = 0;
        for (int b = 0; b < NBLK; b++) { int v = bsum[b]; bsum[b] = acc; acc += v; }
    }
}

__global__ void scan3_k(int* __restrict__ rowptr, const int* __restrict__ bsum) {
    int i = blockIdx.x * blockDim.x + threadIdx.x;
    if (i < NN) rowptr[i] += bsum[i / SCAN_CHUNK];
}

__global__ void scatter_k(const int* __restrict__ ei, const int* __restrict__ rowptr,
                          int* __restrict__ fill, int* __restrict__ esrc) {
    int e = blockIdx.x * blockDim.x + threadIdx.x;
    if (e >= EE) return;
    int d = ei[EE + e];
    int pos = rowptr[d] + atomicAdd(&fill[d], 1);
    esrc[pos] = ei[e];
}

// ---------------- dense lin_l / lin_r ----------------

template <int DIN>
__global__ void gemm_lr_k(const float* __restrict__ x,
                          const float* __restrict__ Wl, const float* __restrict__ bl,
                          const float* __restrict__ Wr, const float* __restrict__ br,
                          float* __restrict__ xl, float* __restrict__ xr) {
    int t = blockIdx.x * blockDim.x + threadIdx.x;
    if (t >= NN * FDIM) return;
    int n = t / FDIM;
    int j = t - n * FDIM;
    const float* xp = x + (size_t)n * DIN;
    float al = bl[j], ar = br[j];
#pragma unroll
    for (int k = 0; k < DIN; k++) {
        float xv = xp[k];
        al = fmaf(xv, Wl[k * FDIM + j], al);
        ar = fmaf(xv, Wr[k * FDIM + j], ar);
    }
    xl[t] = al;
    xr[t] = ar;
}

// ---------------- fused GATv2 layer: wave per destination node, online softmax ----------------
// lane = 16*h + u holds floats [h*48 + 3u, +3) of the [H][C]=192 row.
__global__ void gat_node_k(const float* __restrict__ xl, const float* __restrict__ xr,
                           const int* __restrict__ rowptr, const int* __restrict__ cnt,
                           const int* __restrict__ esrc, const float* __restrict__ att,
                           const float* __restrict__ bias, float* __restrict__ xout) {
    int wid = (blockIdx.x * blockDim.x + threadIdx.x) >> 6;
    int lane = threadIdx.x & 63;
    if (wid >= NN) return;
    int d = wid;
    int h = lane >> 4;
    int u = lane & 15;
    int f0 = h * HID + u * 3;

    float w0 = att[f0], w1 = att[f0 + 1], w2 = att[f0 + 2];
    const float* xrd = xr + (size_t)d * FDIM;
    float r0 = xrd[f0], r1 = xrd[f0 + 1], r2 = xrd[f0 + 2];

    // self-loop initializes the online-softmax state
    const float* xld = xl + (size_t)d * FDIM;
    float a0 = xld[f0], a1 = xld[f0 + 1], a2 = xld[f0 + 2];
    float v0 = a0 + r0; v0 = v0 > 0.f ? v0 : 0.2f * v0;
    float v1 = a1 + r1; v1 = v1 > 0.f ? v1 : 0.2f * v1;
    float v2 = a2 + r2; v2 = v2 > 0.f ? v2 : 0.2f * v2;
    float part = fmaf(v0, w0, fmaf(v1, w1, v2 * w2));
    part += __shfl_xor(part, 1);
    part += __shfl_xor(part, 2);
    part += __shfl_xor(part, 4);
    part += __shfl_xor(part, 8);
    float m = part;         // running max
    float s = 1.0f;         // running denom (self contributes exp(0))
    float o0 = a0, o1 = a1, o2 = a2;

    int start = rowptr[d], deg = cnt[d];
    float na0 = 0.f, na1 = 0.f, na2 = 0.f;
    if (deg > 0) {
        const float* p = xl + (size_t)esrc[start] * FDIM;
        na0 = p[f0]; na1 = p[f0 + 1]; na2 = p[f0 + 2];
    }
    for (int i = 0; i < deg; i++) {
        float ca0 = na0, ca1 = na1, ca2 = na2;
        if (i + 1 < deg) {
            const float* p = xl + (size_t)esrc[start + i + 1] * FDIM;
            na0 = p[f0]; na1 = p[f0 + 1]; na2 = p[f0 + 2];
        }
        v0 = ca0 + r0; v0 = v0 > 0.f ? v0 : 0.2f * v0;
        v1 = ca1 + r1; v1 = v1 > 0.f ? v1 : 0.2f * v1;
        v2 = ca2 + r2; v2 = v2 > 0.f ? v2 : 0.2f * v2;
        part = fmaf(v0, w0, fmaf(v1, w1, v2 * w2));
        part += __shfl_xor(part, 1);
        part += __shfl_xor(part, 2);
        part += __shfl_xor(part, 4);
        part += __shfl_xor(part, 8);
        float l = part;
        float mn = fmaxf(m, l);
        float c = __expf(m - mn);
        float p = __expf(l - mn);
        s = s * c + p;
        o0 = fmaf(o0, c, p * ca0);
        o1 = fmaf(o1, c, p * ca1);
        o2 = fmaf(o2, c, p * ca2);
        m = mn;
    }
    float inv = 1.0f / (s + 1e-16f);
    o0 *= inv; o1 *= inv; o2 *= inv;
    // mean over heads: sum lanes {u, u+16, u+32, u+48}
    o0 += __shfl_xor(o0, 16); o0 += __shfl_xor(o0, 32);
    o1 += __shfl_xor(o1, 16); o1 += __shfl_xor(o1, 32);
    o2 += __shfl_xor(o2, 16); o2 += __shfl_xor(o2, 32);
    if (h == 0) {
        int c0 = u * 3;
        float y0 = 0.25f * o0 + bias[c0];
        float y1 = 0.25f * o1 + bias[c0 + 1];
        float y2 = 0.25f * o2 + bias[c0 + 2];
        y0 = y0 > 0.f ? y0 : expm1f(y0);
        y1 = y1 > 0.f ? y1 : expm1f(y1);
        y2 = y2 > 0.f ? y2 : expm1f(y2);
        float* q = xout + (size_t)d * HID + c0;
        q[0] = y0; q[1] = y1; q[2] = y2;
    }
}

__global__ void head_k(const float* __restrict__ x, const float* __restrict__ w,
                       const float* __restrict__ hb, float* __restrict__ out) {
    int n = blockIdx.x * blockDim.x + threadIdx.x;
    if (n >= NN) return;
    const float* p = x + (size_t)n * HID;
    float acc = 0.f;
#pragma unroll
    for (int c = 0; c < HID; c++) acc = fmaf(p[c], w[c], acc);
    acc += hb[0];
    out[n] = fmaxf(acc, 0.f) + log1pf(expf(-fabsf(acc)));
}

static inline int cdiv(long a, long b) { return (int)((a + b - 1) / b); }

extern "C" void kernel_launch(void* const* d_in, const int* in_sizes, int n_in,
                              void* d_out, int out_size, void* d_ws, size_t ws_size,
                              hipStream_t stream) {
    const float* x0 = (const float*)d_in[0];
    const int* ei = (const int*)d_in[1];
    const float* Wl[3] = {(const float*)d_in[2], (const float*)d_in[8], (const float*)d_in[14]};
    const float* bl[3] = {(const float*)d_in[3], (const float*)d_in[9], (const float*)d_in[15]};
    const float* Wr[3] = {(const float*)d_in[4], (const float*)d_in[10], (const float*)d_in[16]};
    const float* br[3] = {(const float*)d_in[5], (const float*)d_in[11], (const float*)d_in[17]};
    const float* att[3] = {(const float*)d_in[6], (const float*)d_in[12], (const float*)d_in[18]};
    const float* bb[3] = {(const float*)d_in[7], (const float*)d_in[13], (const float*)d_in[19]};
    const float* hw = (const float*)d_in[20];
    const float* hb = (const float*)d_in[21];

    char* ws = (char*)d_ws;
    float* xl = (float*)ws;     ws += (size_t)NN * FDIM * 4;
    float* xr = (float*)ws;     ws += (size_t)NN * FDIM * 4;
    float* bufA = (float*)ws;   ws += (size_t)NN * HID * 4;
    float* bufB = (float*)ws;   ws += (size_t)NN * HID * 4;
    int* rowptr = (int*)ws;     ws += (size_t)NN * 4;
    int* cnt = (int*)ws;        ws += (size_t)NN * 4;
    int* fill = (int*)ws;       ws += (size_t)NN * 4;
    int* esrc = (int*)ws;       ws += (size_t)EE * 4;
    int* bsum = (int*)ws;       ws += (size_t)NBLK * 4;

    // ---- build dst-CSR once (edge structure shared by all layers) ----
    hipMemsetAsync(cnt, 0, (size_t)NN * 4, stream);
    hipMemsetAsync(fill, 0, (size_t)NN * 4, stream);
    hist_k<<<cdiv(EE, 256), 256, 0, stream>>>(ei, cnt);
    scan1_k<<<NBLK, 256, 0, stream>>>(cnt, rowptr, bsum);
    scan2_k<<<1, 64, 0, stream>>>(bsum);
    scan3_k<<<cdiv(NN, 256), 256, 0, stream>>>(rowptr, bsum);
    scatter_k<<<cdiv(EE, 256), 256, 0, stream>>>(ei, rowptr, fill, esrc);

    const float* xin = x0;
    float* bufs[2] = {bufA, bufB};
    for (int l = 0; l < 3; l++) {
        float* xout = bufs[l & 1];
        if (l == 0)
            gemm_lr_k<3><<<cdiv((long)NN * FDIM, 256), 256, 0, stream>>>(
                xin, Wl[0], bl[0], Wr[0], br[0], xl, xr);
        else
            gemm_lr_k<48><<<cdiv((long)NN * FDIM, 256), 256, 0, stream>>>(
                xin, Wl[l], bl[l], Wr[l], br[l], xl, xr);
        gat_node_k<<<cdiv((long)NN * 64, 256), 256, 0, stream>>>(
            xl, xr, rowptr, cnt, esrc, att[l], bb[l], xout);
        xin = xout;
    }
    head_k<<<cdiv(NN, 256), 256, 0, stream>>>(xin, hw, hb, (float*)d_out);
}

// Round 3
// 606.921 us; speedup vs baseline: 3.9559x; 1.8485x over previous
//
#include <hip/hip_runtime.h>
#include <math.h>

#define NN 100000
#define EE 800000
#define NHEADS 4
#define HID 48
#define FDIM (NHEADS * HID)   // 192
#define SCAN_CHUNK 2048
#define NBLK ((NN + SCAN_CHUNK - 1) / SCAN_CHUNK)  // 49

// ---------------- CSR build (by destination), reused across the 3 layers ----------------

__global__ void hist_k(const int* __restrict__ ei, int* __restrict__ cnt) {
    int e = blockIdx.x * blockDim.x + threadIdx.x;
    if (e >= EE) return;
    atomicAdd(&cnt[ei[EE + e]], 1);
}

__global__ void scan1_k(const int* __restrict__ cnt, int* __restrict__ rowptr,
                        int* __restrict__ bsum) {
    __shared__ int lds[256];
    int b = blockIdx.x, t = threadIdx.x;
    int base = b * SCAN_CHUNK + t * 8;
    int v[8], s = 0;
#pragma unroll
    for (int i = 0; i < 8; i++) { v[i] = (base + i < NN) ? cnt[base + i] : 0; s += v[i]; }
    lds[t] = s;
    __syncthreads();
    for (int off = 1; off < 256; off <<= 1) {
        int val = (t >= off) ? lds[t - off] : 0;
        __syncthreads();
        lds[t] += val;
        __syncthreads();
    }
    if (t == 255) bsum[b] = lds[255];
    int run = lds[t] - s;  // exclusive prefix within block
#pragma unroll
    for (int i = 0; i < 8; i++) {
        if (base + i < NN) rowptr[base + i] = run;
        run += v[i];
    }
}

__global__ void scan2_k(int* __restrict__ bsum) {
    if (threadIdx.x == 0 && blockIdx.x == 0) {
        int acc = 0;
        for (int b = 0; b < NBLK; b++) { int v = bsum[b]; bsum[b] = acc; acc += v; }
    }
}

__global__ void scan3_k(int* __restrict__ rowptr, const int* __restrict__ bsum) {
    int i = blockIdx.x * blockDim.x + threadIdx.x;
    if (i < NN) rowptr[i] += bsum[i / SCAN_CHUNK];
}

__global__ void scatter_k(const int* __restrict__ ei, const int* __restrict__ rowptr,
                          int* __restrict__ fill, int* __restrict__ esrc) {
    int e = blockIdx.x * blockDim.x + threadIdx.x;
    if (e >= EE) return;
    int d = ei[EE + e];
    int pos = rowptr[d] + atomicAdd(&fill[d], 1);
    esrc[pos] = ei[e];
}

// ---------------- register-blocked lin_l / lin_r ----------------
// 192 threads, 32 nodes/block. Thread t: f4 = t%48 (float4 col group), nb = t/48.
// Each thread: 8 nodes x 4 cols x {l,r} = 64 f32 accumulators.
template <int DIN>
__launch_bounds__(192)
__global__ void gemm2_k(const float* __restrict__ x,
                        const float* __restrict__ Wl, const float* __restrict__ bl,
                        const float* __restrict__ Wr, const float* __restrict__ br,
                        float* __restrict__ xl, float* __restrict__ xr) {
    __shared__ float xs[32][53];  // stride 53: nb-groups (8-node step) hit distinct banks
    int t = threadIdx.x;
    int f4 = t % 48, nb = t / 48;
    int node0 = blockIdx.x * 32;

    for (int idx = t; idx < 32 * DIN; idx += 192) {
        int n = idx / DIN, k = idx - n * DIN;
        xs[n][k] = x[(size_t)(node0 + n) * DIN + k];
    }
    __syncthreads();

    float4 accl[8], accr[8];
    {
        float4 bl4 = *(const float4*)(bl + f4 * 4);
        float4 br4 = *(const float4*)(br + f4 * 4);
#pragma unroll
        for (int r = 0; r < 8; r++) { accl[r] = bl4; accr[r] = br4; }
    }

#pragma unroll 4
    for (int k = 0; k < DIN; k++) {
        float4 wl4 = *(const float4*)(Wl + k * FDIM + f4 * 4);
        float4 wr4 = *(const float4*)(Wr + k * FDIM + f4 * 4);
#pragma unroll
        for (int r = 0; r < 8; r++) {
            float xv = xs[nb * 8 + r][k];
            accl[r].x = fmaf(xv, wl4.x, accl[r].x);
            accl[r].y = fmaf(xv, wl4.y, accl[r].y);
            accl[r].z = fmaf(xv, wl4.z, accl[r].z);
            accl[r].w = fmaf(xv, wl4.w, accl[r].w);
            accr[r].x = fmaf(xv, wr4.x, accr[r].x);
            accr[r].y = fmaf(xv, wr4.y, accr[r].y);
            accr[r].z = fmaf(xv, wr4.z, accr[r].z);
            accr[r].w = fmaf(xv, wr4.w, accr[r].w);
        }
    }

#pragma unroll
    for (int r = 0; r < 8; r++) {
        size_t n = (size_t)node0 + nb * 8 + r;
        *(float4*)(xl + n * FDIM + f4 * 4) = accl[r];
        *(float4*)(xr + n * FDIM + f4 * 4) = accr[r];
    }
}

// ---------------- fused GATv2 layer: wave per destination node, online softmax ----------------
// lane = 16*h + u holds floats [h*48 + 3u, +3) of the [H][C]=192 row.
__global__ void gat_node_k(const float* __restrict__ xl, const float* __restrict__ xr,
                           const int* __restrict__ rowptr, const int* __restrict__ cnt,
                           const int* __restrict__ esrc, const float* __restrict__ att,
                           const float* __restrict__ bias, float* __restrict__ xout) {
    int wid = (blockIdx.x * blockDim.x + threadIdx.x) >> 6;
    int lane = threadIdx.x & 63;
    if (wid >= NN) return;
    int d = wid;
    int h = lane >> 4;
    int u = lane & 15;
    int f0 = h * HID + u * 3;

    float w0 = att[f0], w1 = att[f0 + 1], w2 = att[f0 + 2];
    const float* xrd = xr + (size_t)d * FDIM;
    float r0 = xrd[f0], r1 = xrd[f0 + 1], r2 = xrd[f0 + 2];

    // self-loop initializes the online-softmax state
    const float* xld = xl + (size_t)d * FDIM;
    float a0 = xld[f0], a1 = xld[f0 + 1], a2 = xld[f0 + 2];
    float v0 = a0 + r0; v0 = v0 > 0.f ? v0 : 0.2f * v0;
    float v1 = a1 + r1; v1 = v1 > 0.f ? v1 : 0.2f * v1;
    float v2 = a2 + r2; v2 = v2 > 0.f ? v2 : 0.2f * v2;
    float part = fmaf(v0, w0, fmaf(v1, w1, v2 * w2));
    part += __shfl_xor(part, 1);
    part += __shfl_xor(part, 2);
    part += __shfl_xor(part, 4);
    part += __shfl_xor(part, 8);
    float m = part;         // running max
    float s = 1.0f;         // running denom (self contributes exp(0))
    float o0 = a0, o1 = a1, o2 = a2;

    int start = rowptr[d], deg = cnt[d];
    float na0 = 0.f, na1 = 0.f, na2 = 0.f;
    if (deg > 0) {
        const float* p = xl + (size_t)esrc[start] * FDIM;
        na0 = p[f0]; na1 = p[f0 + 1]; na2 = p[f0 + 2];
    }
    for (int i = 0; i < deg; i++) {
        float ca0 = na0, ca1 = na1, ca2 = na2;
        if (i + 1 < deg) {
            const float* p = xl + (size_t)esrc[start + i + 1] * FDIM;
            na0 = p[f0]; na1 = p[f0 + 1]; na2 = p[f0 + 2];
        }
        v0 = ca0 + r0; v0 = v0 > 0.f ? v0 : 0.2f * v0;
        v1 = ca1 + r1; v1 = v1 > 0.f ? v1 : 0.2f * v1;
        v2 = ca2 + r2; v2 = v2 > 0.f ? v2 : 0.2f * v2;
        part = fmaf(v0, w0, fmaf(v1, w1, v2 * w2));
        part += __shfl_xor(part, 1);
        part += __shfl_xor(part, 2);
        part += __shfl_xor(part, 4);
        part += __shfl_xor(part, 8);
        float l = part;
        float mn = fmaxf(m, l);
        float c = __expf(m - mn);
        float p = __expf(l - mn);
        s = s * c + p;
        o0 = fmaf(o0, c, p * ca0);
        o1 = fmaf(o1, c, p * ca1);
        o2 = fmaf(o2, c, p * ca2);
        m = mn;
    }
    float inv = 1.0f / (s + 1e-16f);
    o0 *= inv; o1 *= inv; o2 *= inv;
    // mean over heads: sum lanes {u, u+16, u+32, u+48}
    o0 += __shfl_xor(o0, 16); o0 += __shfl_xor(o0, 32);
    o1 += __shfl_xor(o1, 16); o1 += __shfl_xor(o1, 32);
    o2 += __shfl_xor(o2, 16); o2 += __shfl_xor(o2, 32);
    if (h == 0) {
        int c0 = u * 3;
        float y0 = 0.25f * o0 + bias[c0];
        float y1 = 0.25f * o1 + bias[c0 + 1];
        float y2 = 0.25f * o2 + bias[c0 + 2];
        y0 = y0 > 0.f ? y0 : expm1f(y0);
        y1 = y1 > 0.f ? y1 : expm1f(y1);
        y2 = y2 > 0.f ? y2 : expm1f(y2);
        float* q = xout + (size_t)d * HID + c0;
        q[0] = y0; q[1] = y1; q[2] = y2;
    }
}

__global__ void head_k(const float* __restrict__ x, const float* __restrict__ w,
                       const float* __restrict__ hb, float* __restrict__ out) {
    int n = blockIdx.x * blockDim.x + threadIdx.x;
    if (n >= NN) return;
    const float* p = x + (size_t)n * HID;
    float acc = 0.f;
#pragma unroll
    for (int c = 0; c < HID; c++) acc = fmaf(p[c], w[c], acc);
    acc += hb[0];
    out[n] = fmaxf(acc, 0.f) + log1pf(expf(-fabsf(acc)));
}

static inline int cdiv(long a, long b) { return (int)((a + b - 1) / b); }

extern "C" void kernel_launch(void* const* d_in, const int* in_sizes, int n_in,
                              void* d_out, int out_size, void* d_ws, size_t ws_size,
                              hipStream_t stream) {
    const float* x0 = (const float*)d_in[0];
    const int* ei = (const int*)d_in[1];
    const float* Wl[3] = {(const float*)d_in[2], (const float*)d_in[8], (const float*)d_in[14]};
    const float* bl[3] = {(const float*)d_in[3], (const float*)d_in[9], (const float*)d_in[15]};
    const float* Wr[3] = {(const float*)d_in[4], (const float*)d_in[10], (const float*)d_in[16]};
    const float* br[3] = {(const float*)d_in[5], (const float*)d_in[11], (const float*)d_in[17]};
    const float* att[3] = {(const float*)d_in[6], (const float*)d_in[12], (const float*)d_in[18]};
    const float* bb[3] = {(const float*)d_in[7], (const float*)d_in[13], (const float*)d_in[19]};
    const float* hw = (const float*)d_in[20];
    const float* hb = (const float*)d_in[21];

    char* ws = (char*)d_ws;
    float* xl = (float*)ws;     ws += (size_t)NN * FDIM * 4;
    float* xr = (float*)ws;     ws += (size_t)NN * FDIM * 4;
    float* bufA = (float*)ws;   ws += (size_t)NN * HID * 4;
    float* bufB = (float*)ws;   ws += (size_t)NN * HID * 4;
    int* rowptr = (int*)ws;     ws += (size_t)NN * 4;
    int* cnt = (int*)ws;        ws += (size_t)NN * 4;
    int* fill = (int*)ws;       ws += (size_t)NN * 4;
    int* esrc = (int*)ws;       ws += (size_t)EE * 4;
    int* bsum = (int*)ws;       ws += (size_t)NBLK * 4;

    // ---- build dst-CSR once (edge structure shared by all layers) ----
    hipMemsetAsync(cnt, 0, (size_t)NN * 4, stream);
    hipMemsetAsync(fill, 0, (size_t)NN * 4, stream);
    hist_k<<<cdiv(EE, 256), 256, 0, stream>>>(ei, cnt);
    scan1_k<<<NBLK, 256, 0, stream>>>(cnt, rowptr, bsum);
    scan2_k<<<1, 64, 0, stream>>>(bsum);
    scan3_k<<<cdiv(NN, 256), 256, 0, stream>>>(rowptr, bsum);
    scatter_k<<<cdiv(EE, 256), 256, 0, stream>>>(ei, rowptr, fill, esrc);

    const float* xin = x0;
    float* bufs[2] = {bufA, bufB};
    for (int l = 0; l < 3; l++) {
        float* xout = bufs[l & 1];
        if (l == 0)
            gemm2_k<3><<<NN / 32, 192, 0, stream>>>(
                xin, Wl[0], bl[0], Wr[0], br[0], xl, xr);
        else
            gemm2_k<48><<<NN / 32, 192, 0, stream>>>(
                xin, Wl[l], bl[l], Wr[l], br[l], xl, xr);
        gat_node_k<<<cdiv((long)NN * 64, 256), 256, 0, stream>>>(
            xl, xr, rowptr, cnt, esrc, att[l], bb[l], xout);
        xin = xout;
    }
    head_k<<<cdiv(NN, 256), 256, 0, stream>>>(xin, hw, hb, (float*)d_out);
}

// Round 4
// 564.518 us; speedup vs baseline: 4.2530x; 1.0751x over previous
//
#include <hip/hip_runtime.h>
#include <math.h>

#define NN 100000
#define EE 800000
#define NHEADS 4
#define HID 48
#define FDIM (NHEADS * HID)   // 192
#define SCAN_CHUNK 2048
#define NBLK ((NN + SCAN_CHUNK - 1) / SCAN_CHUNK)  // 49

#if __has_builtin(__builtin_amdgcn_exp2f)
#define EXP2(x) __builtin_amdgcn_exp2f(x)
#else
#define EXP2(x) exp2f(x)
#endif

// ---------------- CSR build (by destination), reused across the 3 layers ----------------

__global__ void hist_k(const int* __restrict__ ei, int* __restrict__ cnt) {
    int e = blockIdx.x * blockDim.x + threadIdx.x;
    if (e >= EE) return;
    atomicAdd(&cnt[ei[EE + e]], 1);
}

__global__ void scan1_k(const int* __restrict__ cnt, int* __restrict__ rowptr,
                        int* __restrict__ bsum) {
    __shared__ int lds[256];
    int b = blockIdx.x, t = threadIdx.x;
    int base = b * SCAN_CHUNK + t * 8;
    int v[8], s = 0;
#pragma unroll
    for (int i = 0; i < 8; i++) { v[i] = (base + i < NN) ? cnt[base + i] : 0; s += v[i]; }
    lds[t] = s;
    __syncthreads();
    for (int off = 1; off < 256; off <<= 1) {
        int val = (t >= off) ? lds[t - off] : 0;
        __syncthreads();
        lds[t] += val;
        __syncthreads();
    }
    if (t == 255) bsum[b] = lds[255];
    int run = lds[t] - s;  // exclusive prefix within block
#pragma unroll
    for (int i = 0; i < 8; i++) {
        if (base + i < NN) rowptr[base + i] = run;
        run += v[i];
    }
}

__global__ void scan2_k(int* __restrict__ bsum) {
    if (threadIdx.x == 0 && blockIdx.x == 0) {
        int acc = 0;
        for (int b = 0; b < NBLK; b++) { int v = bsum[b]; bsum[b] = acc; acc += v; }
    }
}

__global__ void scan3_k(int* __restrict__ rowptr, const int* __restrict__ bsum) {
    int i = blockIdx.x * blockDim.x + threadIdx.x;
    if (i < NN) rowptr[i] += bsum[i / SCAN_CHUNK];
}

__global__ void scatter_k(const int* __restrict__ ei, const int* __restrict__ rowptr,
                          int* __restrict__ fill, int* __restrict__ esrc) {
    int e = blockIdx.x * blockDim.x + threadIdx.x;
    if (e >= EE) return;
    int d = ei[EE + e];
    int pos = rowptr[d] + atomicAdd(&fill[d], 1);
    esrc[pos] = ei[e];
}

// ---------------- register-blocked lin_l / lin_r ----------------
template <int DIN>
__launch_bounds__(192)
__global__ void gemm2_k(const float* __restrict__ x,
                        const float* __restrict__ Wl, const float* __restrict__ bl,
                        const float* __restrict__ Wr, const float* __restrict__ br,
                        float* __restrict__ xl, float* __restrict__ xr) {
    __shared__ float xs[32][53];
    int t = threadIdx.x;
    int f4 = t % 48, nb = t / 48;
    int node0 = blockIdx.x * 32;

    for (int idx = t; idx < 32 * DIN; idx += 192) {
        int n = idx / DIN, k = idx - n * DIN;
        xs[n][k] = x[(size_t)(node0 + n) * DIN + k];
    }
    __syncthreads();

    float4 accl[8], accr[8];
    {
        float4 bl4 = *(const float4*)(bl + f4 * 4);
        float4 br4 = *(const float4*)(br + f4 * 4);
#pragma unroll
        for (int r = 0; r < 8; r++) { accl[r] = bl4; accr[r] = br4; }
    }

#pragma unroll 4
    for (int k = 0; k < DIN; k++) {
        float4 wl4 = *(const float4*)(Wl + k * FDIM + f4 * 4);
        float4 wr4 = *(const float4*)(Wr + k * FDIM + f4 * 4);
#pragma unroll
        for (int r = 0; r < 8; r++) {
            float xv = xs[nb * 8 + r][k];
            accl[r].x = fmaf(xv, wl4.x, accl[r].x);
            accl[r].y = fmaf(xv, wl4.y, accl[r].y);
            accl[r].z = fmaf(xv, wl4.z, accl[r].z);
            accl[r].w = fmaf(xv, wl4.w, accl[r].w);
            accr[r].x = fmaf(xv, wr4.x, accr[r].x);
            accr[r].y = fmaf(xv, wr4.y, accr[r].y);
            accr[r].z = fmaf(xv, wr4.z, accr[r].z);
            accr[r].w = fmaf(xv, wr4.w, accr[r].w);
        }
    }

#pragma unroll
    for (int r = 0; r < 8; r++) {
        size_t n = (size_t)node0 + nb * 8 + r;
        *(float4*)(xl + n * FDIM + f4 * 4) = accl[r];
        *(float4*)(xr + n * FDIM + f4 * 4) = accr[r];
    }
}

// ---------------- fused GATv2 layer ----------------
// DPP row_ror rotate-allreduce over each 16-lane row: 4 fused VALU adds, no LDS.
template <int CTRL>
__device__ __forceinline__ float dpp_add(float x) {
    int v = __builtin_amdgcn_update_dpp(0, __float_as_int(x), CTRL, 0xF, 0xF, true);
    return x + __int_as_float(v);
}
__device__ __forceinline__ float red16(float x) {
    x = dpp_add<0x121>(x);  // row_ror:1
    x = dpp_add<0x122>(x);  // row_ror:2
    x = dpp_add<0x124>(x);  // row_ror:4
    x = dpp_add<0x128>(x);  // row_ror:8
    return x;
}

// wave per destination node, online softmax in base-2 domain.
// lane = 16*h + u holds floats [h*48 + 3u, +3) of the [H][C]=192 row.
__global__ void gat_node_k(const float* __restrict__ xl, const float* __restrict__ xr,
                           const int* __restrict__ rowptr, const int* __restrict__ cnt,
                           const int* __restrict__ esrc, const float* __restrict__ att,
                           const float* __restrict__ bias, float* __restrict__ xout) {
    int wid = (blockIdx.x * blockDim.x + threadIdx.x) >> 6;
    int lane = threadIdx.x & 63;
    if (wid >= NN) return;
    int d = wid;
    int h = lane >> 4;
    int u = lane & 15;
    int f0 = h * HID + u * 3;

    const float LOG2E = 1.4426950408889634f;
    float w0 = att[f0] * LOG2E, w1 = att[f0 + 1] * LOG2E, w2 = att[f0 + 2] * LOG2E;
    const float* xrd = xr + (size_t)d * FDIM;
    float r0 = xrd[f0], r1 = xrd[f0 + 1], r2 = xrd[f0 + 2];

    // self-loop initializes the online-softmax state
    const float* xld = xl + (size_t)d * FDIM;
    float a0 = xld[f0], a1 = xld[f0 + 1], a2 = xld[f0 + 2];
    float v0 = a0 + r0; v0 = fmaxf(v0, 0.2f * v0);
    float v1 = a1 + r1; v1 = fmaxf(v1, 0.2f * v1);
    float v2 = a2 + r2; v2 = fmaxf(v2, 0.2f * v2);
    float m = red16(fmaf(v0, w0, fmaf(v1, w1, v2 * w2)));  // running max (base-2 logit)
    float s = 1.0f;
    float o0 = a0, o1 = a1, o2 = a2;

    int start = rowptr[d], deg = cnt[d];

    for (int base = 0; base < deg; base += 64) {
        int rem = deg - base;
        if (rem > 64) rem = 64;
        int my_src = 0;
        if (lane < rem) my_src = esrc[start + base + lane];

        int src_n = __builtin_amdgcn_readlane(my_src, 0);
        const float* pn = xl + (size_t)src_n * FDIM;
        float na0 = pn[f0], na1 = pn[f0 + 1], na2 = pn[f0 + 2];

        for (int i = 0; i < rem; i++) {
            float ca0 = na0, ca1 = na1, ca2 = na2;
            if (i + 1 < rem) {
                int s2 = __builtin_amdgcn_readlane(my_src, i + 1);
                const float* p = xl + (size_t)s2 * FDIM;
                na0 = p[f0]; na1 = p[f0 + 1]; na2 = p[f0 + 2];
            }
            v0 = ca0 + r0; v0 = fmaxf(v0, 0.2f * v0);
            v1 = ca1 + r1; v1 = fmaxf(v1, 0.2f * v1);
            v2 = ca2 + r2; v2 = fmaxf(v2, 0.2f * v2);
            float l = red16(fmaf(v0, w0, fmaf(v1, w1, v2 * w2)));
            float mn = fmaxf(m, l);
            float c = EXP2(m - mn);
            float p2 = EXP2(l - mn);
            s = fmaf(s, c, p2);
            o0 = fmaf(o0, c, p2 * ca0);
            o1 = fmaf(o1, c, p2 * ca1);
            o2 = fmaf(o2, c, p2 * ca2);
            m = mn;
        }
    }

    float inv = 1.0f / (s + 1e-16f);
    o0 *= inv; o1 *= inv; o2 *= inv;
    // mean over heads: sum lanes {u, u+16, u+32, u+48}
    o0 += __shfl_xor(o0, 16); o0 += __shfl_xor(o0, 32);
    o1 += __shfl_xor(o1, 16); o1 += __shfl_xor(o1, 32);
    o2 += __shfl_xor(o2, 16); o2 += __shfl_xor(o2, 32);
    if (h == 0) {
        int c0 = u * 3;
        float y0 = 0.25f * o0 + bias[c0];
        float y1 = 0.25f * o1 + bias[c0 + 1];
        float y2 = 0.25f * o2 + bias[c0 + 2];
        y0 = y0 > 0.f ? y0 : expm1f(y0);
        y1 = y1 > 0.f ? y1 : expm1f(y1);
        y2 = y2 > 0.f ? y2 : expm1f(y2);
        float* q = xout + (size_t)d * HID + c0;
        q[0] = y0; q[1] = y1; q[2] = y2;
    }
}

__global__ void head_k(const float* __restrict__ x, const float* __restrict__ w,
                       const float* __restrict__ hb, float* __restrict__ out) {
    int n = blockIdx.x * blockDim.x + threadIdx.x;
    if (n >= NN) return;
    const float* p = x + (size_t)n * HID;
    float acc = 0.f;
#pragma unroll
    for (int c = 0; c < HID; c++) acc = fmaf(p[c], w[c], acc);
    acc += hb[0];
    out[n] = fmaxf(acc, 0.f) + log1pf(expf(-fabsf(acc)));
}

static inline int cdiv(long a, long b) { return (int)((a + b - 1) / b); }

extern "C" void kernel_launch(void* const* d_in, const int* in_sizes, int n_in,
                              void* d_out, int out_size, void* d_ws, size_t ws_size,
                              hipStream_t stream) {
    const float* x0 = (const float*)d_in[0];
    const int* ei = (const int*)d_in[1];
    const float* Wl[3] = {(const float*)d_in[2], (const float*)d_in[8], (const float*)d_in[14]};
    const float* bl[3] = {(const float*)d_in[3], (const float*)d_in[9], (const float*)d_in[15]};
    const float* Wr[3] = {(const float*)d_in[4], (const float*)d_in[10], (const float*)d_in[16]};
    const float* br[3] = {(const float*)d_in[5], (const float*)d_in[11], (const float*)d_in[17]};
    const float* att[3] = {(const float*)d_in[6], (const float*)d_in[12], (const float*)d_in[18]};
    const float* bb[3] = {(const float*)d_in[7], (const float*)d_in[13], (const float*)d_in[19]};
    const float* hw = (const float*)d_in[20];
    const float* hb = (const float*)d_in[21];

    char* ws = (char*)d_ws;
    float* xl = (float*)ws;     ws += (size_t)NN * FDIM * 4;
    float* xr = (float*)ws;     ws += (size_t)NN * FDIM * 4;
    float* bufA = (float*)ws;   ws += (size_t)NN * HID * 4;
    float* bufB = (float*)ws;   ws += (size_t)NN * HID * 4;
    int* rowptr = (int*)ws;     ws += (size_t)NN * 4;
    int* cnt = (int*)ws;        ws += (size_t)NN * 4;
    int* fill = (int*)ws;       ws += (size_t)NN * 4;
    int* esrc = (int*)ws;       ws += (size_t)EE * 4;
    int* bsum = (int*)ws;       ws += (size_t)NBLK * 4;

    // ---- build dst-CSR once (edge structure shared by all layers) ----
    hipMemsetAsync(cnt, 0, (size_t)NN * 4, stream);
    hipMemsetAsync(fill, 0, (size_t)NN * 4, stream);
    hist_k<<<cdiv(EE, 256), 256, 0, stream>>>(ei, cnt);
    scan1_k<<<NBLK, 256, 0, stream>>>(cnt, rowptr, bsum);
    scan2_k<<<1, 64, 0, stream>>>(bsum);
    scan3_k<<<cdiv(NN, 256), 256, 0, stream>>>(rowptr, bsum);
    scatter_k<<<cdiv(EE, 256), 256, 0, stream>>>(ei, rowptr, fill, esrc);

    const float* xin = x0;
    float* bufs[2] = {bufA, bufB};
    for (int l = 0; l < 3; l++) {
        float* xout = bufs[l & 1];
        if (l == 0)
            gemm2_k<3><<<NN / 32, 192, 0, stream>>>(
                xin, Wl[0], bl[0], Wr[0], br[0], xl, xr);
        else
            gemm2_k<48><<<NN / 32, 192, 0, stream>>>(
                xin, Wl[l], bl[l], Wr[l], br[l], xl, xr);
        gat_node_k<<<cdiv((long)NN * 64, 256), 256, 0, stream>>>(
            xl, xr, rowptr, cnt, esrc, att[l], bb[l], xout);
        xin = xout;
    }
    head_k<<<cdiv(NN, 256), 256, 0, stream>>>(xin, hw, hb, (float*)d_out);
}

// Round 5
// 460.530 us; speedup vs baseline: 5.2134x; 1.2258x over previous
//
#include <hip/hip_runtime.h>
#include <math.h>

#define NN 100000
#define EE 800000
#define NHEADS 4
#define HID 48
#define FDIM (NHEADS * HID)   // 192
#define ROWB 384              // bf16 row bytes (192 * 2)
#define SCAN_CHUNK 2048
#define NBLK ((NN + SCAN_CHUNK - 1) / SCAN_CHUNK)  // 49

typedef unsigned int uint;

#if __has_builtin(__builtin_amdgcn_exp2f)
#define EXP2(x) __builtin_amdgcn_exp2f(x)
#else
#define EXP2(x) exp2f(x)
#endif

struct U3 { uint x, y, z; };  // 12-byte, 4-aligned (avoid HIP uint3 align pitfalls)

// ---------------- CSR build (by destination), reused across the 3 layers ----------------

__global__ void hist_k(const int* __restrict__ ei, int* __restrict__ cnt) {
    int e = blockIdx.x * blockDim.x + threadIdx.x;
    if (e >= EE) return;
    atomicAdd(&cnt[ei[EE + e]], 1);
}

__global__ void scan1_k(const int* __restrict__ cnt, int* __restrict__ rowptr,
                        int* __restrict__ bsum) {
    __shared__ int lds[256];
    int b = blockIdx.x, t = threadIdx.x;
    int base = b * SCAN_CHUNK + t * 8;
    int v[8], s = 0;
#pragma unroll
    for (int i = 0; i < 8; i++) { v[i] = (base + i < NN) ? cnt[base + i] : 0; s += v[i]; }
    lds[t] = s;
    __syncthreads();
    for (int off = 1; off < 256; off <<= 1) {
        int val = (t >= off) ? lds[t - off] : 0;
        __syncthreads();
        lds[t] += val;
        __syncthreads();
    }
    if (t == 255) bsum[b] = lds[255];
    int run = lds[t] - s;
#pragma unroll
    for (int i = 0; i < 8; i++) {
        if (base + i < NN) rowptr[base + i] = run;
        run += v[i];
    }
}

__global__ void scan2_k(int* __restrict__ bsum) {
    if (threadIdx.x == 0 && blockIdx.x == 0) {
        int acc = 0;
        for (int b = 0; b < NBLK; b++) { int v = bsum[b]; bsum[b] = acc; acc += v; }
    }
}

__global__ void scan3_k(int* __restrict__ rowptr, const int* __restrict__ bsum) {
    int i = blockIdx.x * blockDim.x + threadIdx.x;
    if (i < NN) rowptr[i] += bsum[i / SCAN_CHUNK];
}

__global__ void scatter_k(const int* __restrict__ ei, const int* __restrict__ rowptr,
                          int* __restrict__ fill, int* __restrict__ esrc) {
    int e = blockIdx.x * blockDim.x + threadIdx.x;
    if (e >= EE) return;
    int d = ei[EE + e];
    int pos = rowptr[d] + atomicAdd(&fill[d], 1);
    esrc[pos] = ei[e];
}

// ---------------- bf16 helpers ----------------

__device__ __forceinline__ uint f2bf(float x) {   // RTN-even, returns 16-bit value
    uint u = __float_as_uint(x);
    return (u + 0x7FFFu + ((u >> 16) & 1u)) >> 16;
}
__device__ __forceinline__ float bfl(uint u) { return __uint_as_float(u << 16); }
__device__ __forceinline__ float bfh(uint u) { return __uint_as_float(u & 0xFFFF0000u); }

// ---------------- register-blocked lin_l / lin_r, bf16 outputs ----------------
template <int DIN>
__launch_bounds__(192)
__global__ void gemm2_k(const float* __restrict__ x,
                        const float* __restrict__ Wl, const float* __restrict__ bl,
                        const float* __restrict__ Wr, const float* __restrict__ br,
                        uint* __restrict__ xlb, uint* __restrict__ xrb) {
    __shared__ float xs[32][53];
    int t = threadIdx.x;
    int f4 = t % 48, nb = t / 48;
    int node0 = blockIdx.x * 32;

    for (int idx = t; idx < 32 * DIN; idx += 192) {
        int n = idx / DIN, k = idx - n * DIN;
        xs[n][k] = x[(size_t)(node0 + n) * DIN + k];
    }
    __syncthreads();

    float4 accl[8], accr[8];
    {
        float4 bl4 = *(const float4*)(bl + f4 * 4);
        float4 br4 = *(const float4*)(br + f4 * 4);
#pragma unroll
        for (int r = 0; r < 8; r++) { accl[r] = bl4; accr[r] = br4; }
    }

#pragma unroll 4
    for (int k = 0; k < DIN; k++) {
        float4 wl4 = *(const float4*)(Wl + k * FDIM + f4 * 4);
        float4 wr4 = *(const float4*)(Wr + k * FDIM + f4 * 4);
#pragma unroll
        for (int r = 0; r < 8; r++) {
            float xv = xs[nb * 8 + r][k];
            accl[r].x = fmaf(xv, wl4.x, accl[r].x);
            accl[r].y = fmaf(xv, wl4.y, accl[r].y);
            accl[r].z = fmaf(xv, wl4.z, accl[r].z);
            accl[r].w = fmaf(xv, wl4.w, accl[r].w);
            accr[r].x = fmaf(xv, wr4.x, accr[r].x);
            accr[r].y = fmaf(xv, wr4.y, accr[r].y);
            accr[r].z = fmaf(xv, wr4.z, accr[r].z);
            accr[r].w = fmaf(xv, wr4.w, accr[r].w);
        }
    }

#pragma unroll
    for (int r = 0; r < 8; r++) {
        size_t n = (size_t)node0 + nb * 8 + r;
        uint2 pl, pr;
        pl.x = f2bf(accl[r].x) | (f2bf(accl[r].y) << 16);
        pl.y = f2bf(accl[r].z) | (f2bf(accl[r].w) << 16);
        pr.x = f2bf(accr[r].x) | (f2bf(accr[r].y) << 16);
        pr.y = f2bf(accr[r].z) | (f2bf(accr[r].w) << 16);
        *(uint2*)((char*)xlb + n * ROWB + f4 * 8) = pl;
        *(uint2*)((char*)xrb + n * ROWB + f4 * 8) = pr;
    }
}

// ---------------- fused GATv2 layer: wave per dst node, 2 edges per iteration ----------------
// DPP 8-lane allreduce: half_mirror + quad_perm xor2 + quad_perm xor1 (within each 8-lane group)
template <int CTRL>
__device__ __forceinline__ float dpp_add(float x) {
    int v = __builtin_amdgcn_update_dpp(0, __float_as_int(x), CTRL, 0xF, 0xF, true);
    return x + __int_as_float(v);
}
__device__ __forceinline__ float red8(float x) {
    x = dpp_add<0x141>(x);  // row_half_mirror: i <-> 7-i within each 8
    x = dpp_add<0x04E>(x);  // quad_perm [2,3,0,1] = xor 2
    x = dpp_add<0x0B1>(x);  // quad_perm [1,0,3,2] = xor 1
    return x;
}

// lane = 32*half + 8*h + j ; lane holds features [h*48 + j*6, +6) of one edge's row.
// Halves process even/odd edges with independent online-softmax states, merged at the end.
__global__ void gat_node_k(const uint* __restrict__ xlb, const uint* __restrict__ xrb,
                           const int* __restrict__ rowptr, const int* __restrict__ cnt,
                           const int* __restrict__ esrc, const float* __restrict__ att,
                           const float* __restrict__ bias, float* __restrict__ xout) {
    int wid = (blockIdx.x * blockDim.x + threadIdx.x) >> 6;
    int lane = threadIdx.x & 63;
    if (wid >= NN) return;
    int d = wid;
    int half = lane >> 5;
    int hb = lane & 31;
    int h = hb >> 3;
    int j = hb & 7;
    int boff = h * 96 + j * 12;      // byte offset of this lane's 6 bf16 features
    int half4 = half << 2;

    const float LOG2E = 1.4426950408889634f;
    const float* ap = att + h * HID + j * 6;
    float w0 = ap[0] * LOG2E, w1 = ap[1] * LOG2E, w2 = ap[2] * LOG2E;
    float w3 = ap[3] * LOG2E, w4 = ap[4] * LOG2E, w5 = ap[5] * LOG2E;

    const char* xlc = (const char*)xlb;
    const char* xrc = (const char*)xrb;

    U3 ur = *(const U3*)(xrc + (size_t)d * ROWB + boff);
    float r0 = bfl(ur.x), r1 = bfh(ur.x), r2 = bfl(ur.y);
    float r3 = bfh(ur.y), r4 = bfl(ur.z), r5 = bfh(ur.z);

    // self-loop edge
    U3 us = *(const U3*)(xlc + (size_t)d * ROWB + boff);
    float a0 = bfl(us.x), a1 = bfh(us.x), a2 = bfl(us.y);
    float a3 = bfh(us.y), a4 = bfl(us.z), a5 = bfh(us.z);
    float v0 = a0 + r0; v0 = fmaxf(v0, 0.2f * v0);
    float v1 = a1 + r1; v1 = fmaxf(v1, 0.2f * v1);
    float v2 = a2 + r2; v2 = fmaxf(v2, 0.2f * v2);
    float v3 = a3 + r3; v3 = fmaxf(v3, 0.2f * v3);
    float v4 = a4 + r4; v4 = fmaxf(v4, 0.2f * v4);
    float v5 = a5 + r5; v5 = fmaxf(v5, 0.2f * v5);
    float lself = red8(fmaf(v0, w0, fmaf(v1, w1, fmaf(v2, w2,
                       fmaf(v3, w3, fmaf(v4, w4, v5 * w5))))));

    // half A starts with the self-loop; half B starts empty
    float m = half ? -3.0e38f : lself;
    float s = half ? 0.0f : 1.0f;
    float o0 = half ? 0.f : a0, o1 = half ? 0.f : a1, o2 = half ? 0.f : a2;
    float o3 = half ? 0.f : a3, o4 = half ? 0.f : a4, o5 = half ? 0.f : a5;

    int start = rowptr[d], deg = cnt[d];

    for (int cb = 0; cb < deg; cb += 64) {
        int rem = deg - cb; if (rem > 64) rem = 64;
        int my_src = 0;
        if (lane < rem) my_src = esrc[start + cb + lane];
        int npairs = (rem + 1) >> 1;

        int src = __builtin_amdgcn_ds_bpermute(half4, my_src);
        uint off = (uint)src * (uint)ROWB + (uint)boff;
        U3 cur = *(const U3*)(xlc + off);

        for (int i = 0; i + 1 < npairs; i++) {
            int nsrc = __builtin_amdgcn_ds_bpermute(((i + 1) << 3) + half4, my_src);
            uint noff = (uint)nsrc * (uint)ROWB + (uint)boff;
            U3 nxt = *(const U3*)(xlc + noff);

            float ca0 = bfl(cur.x), ca1 = bfh(cur.x), ca2 = bfl(cur.y);
            float ca3 = bfh(cur.y), ca4 = bfl(cur.z), ca5 = bfh(cur.z);
            v0 = ca0 + r0; v0 = fmaxf(v0, 0.2f * v0);
            v1 = ca1 + r1; v1 = fmaxf(v1, 0.2f * v1);
            v2 = ca2 + r2; v2 = fmaxf(v2, 0.2f * v2);
            v3 = ca3 + r3; v3 = fmaxf(v3, 0.2f * v3);
            v4 = ca4 + r4; v4 = fmaxf(v4, 0.2f * v4);
            v5 = ca5 + r5; v5 = fmaxf(v5, 0.2f * v5);
            float l = red8(fmaf(v0, w0, fmaf(v1, w1, fmaf(v2, w2,
                           fmaf(v3, w3, fmaf(v4, w4, v5 * w5))))));
            float mn = fmaxf(m, l);
            float c = EXP2(m - mn);
            float p = EXP2(l - mn);
            s = fmaf(s, c, p);
            o0 = fmaf(o0, c, p * ca0);
            o1 = fmaf(o1, c, p * ca1);
            o2 = fmaf(o2, c, p * ca2);
            o3 = fmaf(o3, c, p * ca3);
            o4 = fmaf(o4, c, p * ca4);
            o5 = fmaf(o5, c, p * ca5);
            m = mn;
            cur = nxt;
        }
        {   // peeled final pair (only place a validity guard is needed)
            int eid = ((npairs - 1) << 1) + half;
            bool valid = eid < rem;
            float ca0 = bfl(cur.x), ca1 = bfh(cur.x), ca2 = bfl(cur.y);
            float ca3 = bfh(cur.y), ca4 = bfl(cur.z), ca5 = bfh(cur.z);
            v0 = ca0 + r0; v0 = fmaxf(v0, 0.2f * v0);
            v1 = ca1 + r1; v1 = fmaxf(v1, 0.2f * v1);
            v2 = ca2 + r2; v2 = fmaxf(v2, 0.2f * v2);
            v3 = ca3 + r3; v3 = fmaxf(v3, 0.2f * v3);
            v4 = ca4 + r4; v4 = fmaxf(v4, 0.2f * v4);
            v5 = ca5 + r5; v5 = fmaxf(v5, 0.2f * v5);
            float l = red8(fmaf(v0, w0, fmaf(v1, w1, fmaf(v2, w2,
                           fmaf(v3, w3, fmaf(v4, w4, v5 * w5))))));
            float mn = valid ? fmaxf(m, l) : m;
            float p = valid ? EXP2(l - mn) : 0.0f;
            float c = EXP2(m - mn);
            s = fmaf(s, c, p);
            o0 = fmaf(o0, c, p * ca0);
            o1 = fmaf(o1, c, p * ca1);
            o2 = fmaf(o2, c, p * ca2);
            o3 = fmaf(o3, c, p * ca3);
            o4 = fmaf(o4, c, p * ca4);
            o5 = fmaf(o5, c, p * ca5);
            m = mn;
        }
    }

    // merge the two halves' online-softmax states
    float m2 = __shfl_xor(m, 32);
    float s2 = __shfl_xor(s, 32);
    float mn = fmaxf(m, m2);
    float c1 = EXP2(m - mn), c2 = EXP2(m2 - mn);
    float sm = fmaf(s, c1, s2 * c2);
    float inv = 1.0f / (sm + 1e-16f);
    float q0 = fmaf(o0, c1, __shfl_xor(o0, 32) * c2) * inv;
    float q1 = fmaf(o1, c1, __shfl_xor(o1, 32) * c2) * inv;
    float q2 = fmaf(o2, c1, __shfl_xor(o2, 32) * c2) * inv;
    float q3 = fmaf(o3, c1, __shfl_xor(o3, 32) * c2) * inv;
    float q4 = fmaf(o4, c1, __shfl_xor(o4, 32) * c2) * inv;
    float q5 = fmaf(o5, c1, __shfl_xor(o5, 32) * c2) * inv;

    // mean over heads: sum lane groups h=0..3 (xor 8, xor 16)
    q0 += __shfl_xor(q0, 8); q0 += __shfl_xor(q0, 16);
    q1 += __shfl_xor(q1, 8); q1 += __shfl_xor(q1, 16);
    q2 += __shfl_xor(q2, 8); q2 += __shfl_xor(q2, 16);
    q3 += __shfl_xor(q3, 8); q3 += __shfl_xor(q3, 16);
    q4 += __shfl_xor(q4, 8); q4 += __shfl_xor(q4, 16);
    q5 += __shfl_xor(q5, 8); q5 += __shfl_xor(q5, 16);

    if (lane < 8) {
        const float* bp = bias + j * 6;
        float y0 = fmaf(q0, 0.25f, bp[0]);
        float y1 = fmaf(q1, 0.25f, bp[1]);
        float y2 = fmaf(q2, 0.25f, bp[2]);
        float y3 = fmaf(q3, 0.25f, bp[3]);
        float y4 = fmaf(q4, 0.25f, bp[4]);
        float y5 = fmaf(q5, 0.25f, bp[5]);
        y0 = y0 > 0.f ? y0 : (EXP2(y0 * LOG2E) - 1.0f);
        y1 = y1 > 0.f ? y1 : (EXP2(y1 * LOG2E) - 1.0f);
        y2 = y2 > 0.f ? y2 : (EXP2(y2 * LOG2E) - 1.0f);
        y3 = y3 > 0.f ? y3 : (EXP2(y3 * LOG2E) - 1.0f);
        y4 = y4 > 0.f ? y4 : (EXP2(y4 * LOG2E) - 1.0f);
        y5 = y5 > 0.f ? y5 : (EXP2(y5 * LOG2E) - 1.0f);
        float* qo = xout + (size_t)d * HID + j * 6;
        *(float2*)(qo) = make_float2(y0, y1);
        *(float2*)(qo + 2) = make_float2(y2, y3);
        *(float2*)(qo + 4) = make_float2(y4, y5);
    }
}

__global__ void head_k(const float* __restrict__ x, const float* __restrict__ w,
                       const float* __restrict__ hb, float* __restrict__ out) {
    int n = blockIdx.x * blockDim.x + threadIdx.x;
    if (n >= NN) return;
    const float* p = x + (size_t)n * HID;
    float acc = 0.f;
#pragma unroll
    for (int c = 0; c < HID; c++) acc = fmaf(p[c], w[c], acc);
    acc += hb[0];
    out[n] = fmaxf(acc, 0.f) + log1pf(expf(-fabsf(acc)));
}

static inline int cdiv(long a, long b) { return (int)((a + b - 1) / b); }

extern "C" void kernel_launch(void* const* d_in, const int* in_sizes, int n_in,
                              void* d_out, int out_size, void* d_ws, size_t ws_size,
                              hipStream_t stream) {
    const float* x0 = (const float*)d_in[0];
    const int* ei = (const int*)d_in[1];
    const float* Wl[3] = {(const float*)d_in[2], (const float*)d_in[8], (const float*)d_in[14]};
    const float* bl[3] = {(const float*)d_in[3], (const float*)d_in[9], (const float*)d_in[15]};
    const float* Wr[3] = {(const float*)d_in[4], (const float*)d_in[10], (const float*)d_in[16]};
    const float* br[3] = {(const float*)d_in[5], (const float*)d_in[11], (const float*)d_in[17]};
    const float* att[3] = {(const float*)d_in[6], (const float*)d_in[12], (const float*)d_in[18]};
    const float* bb[3] = {(const float*)d_in[7], (const float*)d_in[13], (const float*)d_in[19]};
    const float* hw = (const float*)d_in[20];
    const float* hb = (const float*)d_in[21];

    char* ws = (char*)d_ws;
    uint* xlb = (uint*)ws;      ws += (size_t)NN * ROWB;
    uint* xrb = (uint*)ws;      ws += (size_t)NN * ROWB;
    float* bufA = (float*)ws;   ws += (size_t)NN * HID * 4;
    float* bufB = (float*)ws;   ws += (size_t)NN * HID * 4;
    int* rowptr = (int*)ws;     ws += (size_t)NN * 4;
    int* cnt = (int*)ws;        ws += (size_t)NN * 4;
    int* fill = (int*)ws;       ws += (size_t)NN * 4;
    int* esrc = (int*)ws;       ws += (size_t)EE * 4;
    int* bsum = (int*)ws;       ws += (size_t)NBLK * 4;

    // ---- build dst-CSR once ----
    hipMemsetAsync(cnt, 0, (size_t)NN * 4, stream);
    hipMemsetAsync(fill, 0, (size_t)NN * 4, stream);
    hist_k<<<cdiv(EE, 256), 256, 0, stream>>>(ei, cnt);
    scan1_k<<<NBLK, 256, 0, stream>>>(cnt, rowptr, bsum);
    scan2_k<<<1, 64, 0, stream>>>(bsum);
    scan3_k<<<cdiv(NN, 256), 256, 0, stream>>>(rowptr, bsum);
    scatter_k<<<cdiv(EE, 256), 256, 0, stream>>>(ei, rowptr, fill, esrc);

    const float* xin = x0;
    float* bufs[2] = {bufA, bufB};
    for (int l = 0; l < 3; l++) {
        float* xout = bufs[l & 1];
        if (l == 0)
            gemm2_k<3><<<NN / 32, 192, 0, stream>>>(
                xin, Wl[0], bl[0], Wr[0], br[0], xlb, xrb);
        else
            gemm2_k<48><<<NN / 32, 192, 0, stream>>>(
                xin, Wl[l], bl[l], Wr[l], br[l], xlb, xrb);
        gat_node_k<<<cdiv((long)NN * 64, 256), 256, 0, stream>>>(
            xlb, xrb, rowptr, cnt, esrc, att[l], bb[l], xout);
        xin = xout;
    }
    head_k<<<cdiv(NN, 256), 256, 0, stream>>>(xin, hw, hb, (float*)d_out);
}